// Round 1
// baseline (1387.535 us; speedup 1.0000x reference)
//
#include <hip/hip_runtime.h>
#include <cstdio>

typedef long long ll;

#define BB 4
#define NN 4096
#define CC 256
#define HH 512
#define GNUM 4
#define GS1 128
#define KNN 10

// ---------------- generic tiled f32 GEMM ----------------
// C[m][n] = sum_k A[m][k]*B[k][n]   (ATRANS: A stored [k][m] with row stride lda)
// EPI: 0 = store, 1 = +bias store, 2 = +bias relu store, 3 = +bias accumulate (C+=),
//      4 = +bias, transposed store: out[(z*N+n)*M+m] = val + pre[same]
template<bool ATRANS, int EPI>
__global__ __launch_bounds__(256) void gemm_k(
    const float* __restrict__ A, const float* __restrict__ Bw,
    const float* __restrict__ bias, float* __restrict__ Cout,
    const float* __restrict__ pre,
    int M, int N, int K, int lda, ll strideA, ll strideC)
{
  const int z = blockIdx.z;
  A += (ll)z * strideA;
  const int bm = blockIdx.y * 64;
  const int bn = blockIdx.x * 64;
  __shared__ float As[16][64];
  __shared__ float Bs[16][64];
  const int tid = threadIdx.x;
  const int tx = tid & 15, ty = tid >> 4;
  float acc[4][4] = {};

  for (int k0 = 0; k0 < K; k0 += 16) {
    if (ATRANS) {
      #pragma unroll
      for (int i = tid; i < 16 * 64; i += 256) {
        int k = i >> 6, m = i & 63;
        As[k][m] = A[(ll)(k0 + k) * lda + (bm + m)];
      }
    } else {
      #pragma unroll
      for (int i = tid; i < 16 * 64; i += 256) {
        int m = i >> 4, k = i & 15;
        As[k][m] = A[(ll)(bm + m) * lda + (k0 + k)];
      }
    }
    #pragma unroll
    for (int i = tid; i < 16 * 64; i += 256) {
      int k = i >> 6, n = i & 63;
      Bs[k][n] = Bw[(ll)(k0 + k) * N + (bn + n)];
    }
    __syncthreads();
    #pragma unroll
    for (int kk = 0; kk < 16; ++kk) {
      const float4 av = *reinterpret_cast<const float4*>(&As[kk][ty * 4]);
      const float4 bv = *reinterpret_cast<const float4*>(&Bs[kk][tx * 4]);
      const float ar[4] = {av.x, av.y, av.z, av.w};
      const float br[4] = {bv.x, bv.y, bv.z, bv.w};
      #pragma unroll
      for (int i = 0; i < 4; ++i)
        #pragma unroll
        for (int j = 0; j < 4; ++j)
          acc[i][j] = fmaf(ar[i], br[j], acc[i][j]);
    }
    __syncthreads();
  }

  const int m0 = bm + ty * 4, n0 = bn + tx * 4;
  const ll cb = (ll)z * strideC;
  #pragma unroll
  for (int i = 0; i < 4; ++i) {
    #pragma unroll
    for (int j = 0; j < 4; ++j) {
      const int m = m0 + i, n = n0 + j;
      float val = acc[i][j];
      if (EPI != 0) val += bias[n];
      if (EPI == 2) val = fmaxf(val, 0.f);
      if (EPI == 4) {
        const size_t o = ((size_t)z * N + n) * (size_t)M + m;
        Cout[o] = val + pre[o];
      } else if (EPI == 3) {
        Cout[cb + (ll)m * N + n] += val;
      } else {
        Cout[cb + (ll)m * N + n] = val;
      }
    }
  }
}

// ---------------- softmax over n-axis for a1: P is (B, N, 4, 128) ----------------
__global__ __launch_bounds__(1024) void softmax1_k(float* __restrict__ P) {
  const int bg = blockIdx.x;
  const int b = bg >> 2, g = bg & 3;
  const int d = threadIdx.x & 127, ns = threadIdx.x >> 7; // 8 segments of 512 rows
  const float scale = 0.08838834764831845f;               // 1/sqrt(128)
  __shared__ float red[8][128];
  __shared__ float gmax[128], gsum[128];
  const size_t base = ((size_t)b * NN * GNUM + g) * GS1 + d; // + n*512

  float mx = -3.4e38f;
  for (int n = ns * 512; n < ns * 512 + 512; ++n)
    mx = fmaxf(mx, P[base + (size_t)n * 512]);
  red[ns][d] = mx;
  __syncthreads();
  if (ns == 0) {
    float m = red[0][d];
    #pragma unroll
    for (int s = 1; s < 8; ++s) m = fmaxf(m, red[s][d]);
    gmax[d] = m;
  }
  __syncthreads();
  const float m = gmax[d];
  float sum = 0.f;
  for (int n = ns * 512; n < ns * 512 + 512; ++n)
    sum += expf((P[base + (size_t)n * 512] - m) * scale);
  __syncthreads();
  red[ns][d] = sum;
  __syncthreads();
  if (ns == 0) {
    float t = 0.f;
    #pragma unroll
    for (int s = 0; s < 8; ++s) t += red[s][d];
    gsum[d] = t;
  }
  __syncthreads();
  const float inv = 1.0f / gsum[d];
  for (int n = ns * 512; n < ns * 512 + 512; ++n) {
    const size_t o = base + (size_t)n * 512;
    P[o] = expf((P[o] - m) * scale) * inv;
  }
}

// ---------------- softmax over row-axis for a2: A2 is (B, 1024, 512) ----------------
__global__ __launch_bounds__(1024) void softmax2_k(float* __restrict__ A2) {
  const int bh = blockIdx.x;
  const int b = bh >> 2, hb = bh & 3;
  const int h = hb * 128 + (threadIdx.x & 127), rs = threadIdx.x >> 7; // 8 segs of 128 rows
  const float scale = 0.044194173824159216f; // 1/sqrt(512)
  __shared__ float red[8][128];
  __shared__ float gmax[128], gsum[128];
  const int hl = threadIdx.x & 127;
  const size_t base = (size_t)b * 1024 * HH + h;

  float mx = -3.4e38f;
  for (int r = rs * 128; r < rs * 128 + 128; ++r)
    mx = fmaxf(mx, A2[base + (size_t)r * HH]);
  red[rs][hl] = mx;
  __syncthreads();
  if (rs == 0) {
    float m = red[0][hl];
    #pragma unroll
    for (int s = 1; s < 8; ++s) m = fmaxf(m, red[s][hl]);
    gmax[hl] = m;
  }
  __syncthreads();
  const float m = gmax[hl];
  float sum = 0.f;
  for (int r = rs * 128; r < rs * 128 + 128; ++r)
    sum += expf((A2[base + (size_t)r * HH] - m) * scale);
  __syncthreads();
  red[rs][hl] = sum;
  __syncthreads();
  if (rs == 0) {
    float t = 0.f;
    #pragma unroll
    for (int s = 0; s < 8; ++s) t += red[s][hl];
    gsum[hl] = t;
  }
  __syncthreads();
  const float inv = 1.0f / gsum[hl];
  for (int r = rs * 128; r < rs * 128 + 128; ++r) {
    const size_t o = base + (size_t)r * HH;
    A2[o] = expf((A2[o] - m) * scale) * inv;
  }
}

// ---------------- KNN top-10 (smallest dist, ties -> lowest index) ----------------
__global__ __launch_bounds__(256) void knn_k(const float* __restrict__ xyz, int* __restrict__ idx) {
  const int bn = blockIdx.x;
  const int b = bn >> 12, n = bn & (NN - 1);
  const float* xb = xyz + (size_t)b * NN * 3;
  const float qx = xb[n * 3], qy = xb[n * 3 + 1], qz = xb[n * 3 + 2];
  const float sq = fmaf(qz, qz, fmaf(qy, qy, qx * qx));

  float bd[KNN];
  int bi[KNN];
  #pragma unroll
  for (int k = 0; k < KNN; ++k) { bd[k] = 3.4e38f; bi[k] = 1 << 30; }

  for (int m = threadIdx.x; m < NN; m += 256) {
    const float cx = xb[m * 3], cy = xb[m * 3 + 1], cz = xb[m * 3 + 2];
    const float sm = fmaf(cz, cz, fmaf(cy, cy, cx * cx));
    const float dot = fmaf(cz, qz, fmaf(cy, qy, cx * qx));
    const float dist = (sq + sm) - 2.0f * dot;
    if (dist < bd[KNN - 1]) {
      bd[KNN - 1] = dist; bi[KNN - 1] = m;
      #pragma unroll
      for (int k = KNN - 1; k >= 1; --k) {
        if (bd[k] < bd[k - 1]) {
          float td = bd[k]; bd[k] = bd[k - 1]; bd[k - 1] = td;
          int ti = bi[k]; bi[k] = bi[k - 1]; bi[k - 1] = ti;
        }
      }
    }
  }

  __shared__ float md[256][KNN];
  __shared__ int mi[256][KNN];
  const int tid = threadIdx.x;
  #pragma unroll
  for (int k = 0; k < KNN; ++k) { md[tid][k] = bd[k]; mi[tid][k] = bi[k]; }
  __syncthreads();

  for (int s = 1; s < 256; s <<= 1) {
    if ((tid & (2 * s - 1)) == 0) {
      float od[KNN]; int oi[KNN];
      int pa = 0, pb = 0;
      #pragma unroll
      for (int k = 0; k < KNN; ++k) {
        const float da = md[tid][pa], db = md[tid + s][pb];
        const int ia = mi[tid][pa], ib = mi[tid + s][pb];
        const bool takea = (da < db) || (da == db && ia < ib);
        od[k] = takea ? da : db;
        oi[k] = takea ? ia : ib;
        if (takea) ++pa; else ++pb;
      }
      #pragma unroll
      for (int k = 0; k < KNN; ++k) { md[tid][k] = od[k]; mi[tid][k] = oi[k]; }
    }
    __syncthreads();
  }
  if (tid < KNN) idx[(size_t)bn * KNN + tid] = mi[0][tid];
}

// ---------------- pos-enc hidden mean: hmean = mean_k relu((q - nbr) @ fd1 + b1) ----------------
__global__ __launch_bounds__(256) void posenc_k(const float* __restrict__ xyz, const int* __restrict__ idx,
                                                const float* __restrict__ fd1w, const float* __restrict__ fd1b,
                                                float* __restrict__ hmean) {
  const int bn = blockIdx.x;
  const int b = bn >> 12, n = bn & (NN - 1);
  const float* xb = xyz + (size_t)b * NN * 3;
  const float qx = xb[n * 3], qy = xb[n * 3 + 1], qz = xb[n * 3 + 2];
  __shared__ float dxyz[KNN][3];
  if (threadIdx.x < KNN) {
    const int m = idx[(size_t)bn * KNN + threadIdx.x];
    dxyz[threadIdx.x][0] = qx - xb[m * 3];
    dxyz[threadIdx.x][1] = qy - xb[m * 3 + 1];
    dxyz[threadIdx.x][2] = qz - xb[m * 3 + 2];
  }
  __syncthreads();
  for (int h = threadIdx.x; h < HH; h += 256) {
    const float w0 = fd1w[h], w1 = fd1w[HH + h], w2 = fd1w[2 * HH + h], bb = fd1b[h];
    float acc = 0.f;
    #pragma unroll
    for (int k = 0; k < KNN; ++k)
      acc += fmaxf(fmaf(dxyz[k][2], w2, fmaf(dxyz[k][1], w1, dxyz[k][0] * w0)) + bb, 0.f);
    hmean[(size_t)bn * HH + h] = acc * 0.1f;
  }
}

// ---------------- res = (attn1 + attn2_tiled) * (v + posenc) ----------------
__global__ __launch_bounds__(256) void res_k(const float* __restrict__ P, const float* __restrict__ A2,
                                             const float* __restrict__ V, float* __restrict__ R) {
  const size_t i4 = (size_t)blockIdx.x * 256 + threadIdx.x;
  const size_t i = i4 * 4;
  const size_t bn = i >> 9;
  const int b = (int)(bn >> 12), n = (int)(bn & (NN - 1));
  const int h = (int)(i & (HH - 1));
  const size_t j = ((size_t)b * 1024 + (n & 1023)) * HH + h;
  const float4 p = *reinterpret_cast<const float4*>(P + i);
  const float4 a = *reinterpret_cast<const float4*>(A2 + j);
  const float4 v = *reinterpret_cast<const float4*>(V + i);
  float4 r;
  r.x = (p.x + a.x) * v.x;
  r.y = (p.y + a.y) * v.y;
  r.z = (p.z + a.z) * v.z;
  r.w = (p.w + a.w) * v.w;
  *reinterpret_cast<float4*>(R + i) = r;
}

__global__ void sub_k(const float* __restrict__ a, const float* __restrict__ b, float* __restrict__ o, int n) {
  const int i = blockIdx.x * 256 + threadIdx.x;
  if (i < n) o[i] = a[i] - b[i];
}

__global__ void copy_k(const float* __restrict__ a, float* __restrict__ o, int n) {
  const int i = blockIdx.x * 256 + threadIdx.x;
  if (i < n) o[i] = a[i];
}

extern "C" void kernel_launch(void* const* d_in, const int* in_sizes, int n_in,
                              void* d_out, int out_size, void* d_ws, size_t ws_size,
                              hipStream_t stream) {
  const float* features = (const float*)d_in[0];
  const float* xyz      = (const float*)d_in[1];
  const float* fc1_w    = (const float*)d_in[2];
  const float* fc1_b    = (const float*)d_in[3];
  const float* fc2_w    = (const float*)d_in[4];
  const float* fc2_b    = (const float*)d_in[5];
  const float* fd1_w    = (const float*)d_in[6];
  const float* fd1_b    = (const float*)d_in[7];
  const float* fd2_w    = (const float*)d_in[8];
  const float* fd2_b    = (const float*)d_in[9];
  const float* fg1_w    = (const float*)d_in[10];
  const float* fg1_b    = (const float*)d_in[11];
  const float* fg2_w    = (const float*)d_in[12];
  const float* fg2_b    = (const float*)d_in[13];
  const float* fgh1_w   = (const float*)d_in[14];
  const float* fgh1_b   = (const float*)d_in[15];
  const float* fgh2_w   = (const float*)d_in[16];
  const float* fgh2_b   = (const float*)d_in[17];
  const float* wqs      = (const float*)d_in[18];
  const float* wks      = (const float*)d_in[19];
  const float* wvs      = (const float*)d_in[20];
  const float* wqs2     = (const float*)d_in[21];
  const float* wks2     = (const float*)d_in[22];
  float* out = (float*)d_out;

  const size_t BNH = (size_t)BB * NN * HH;        // 8388608
  float* X   = (float*)d_ws;                      // x, later res
  float* P   = X + BNH;                           // T1 -> A1 -> softmaxed attn1
  float* Q   = P + BNH;                           // U1, later hmean
  float* V   = Q + BNH;                           // v, then += posenc
  float* S1  = V + BNH;                           // qk2 -> A2 -> softmaxed attn2
  float* S2  = S1 + (size_t)BB * 1024 * HH;       // U2
  float* WD  = S2 + (size_t)BB * 1024 * HH;       // wqs-wks (512x512)
  float* WD2 = WD + HH * HH;                      // wqs2-wks2 (128x128)
  int*   IDX = (int*)(WD2 + GS1 * GS1);           // knn indices
  const size_t need = ((char*)(IDX + (size_t)BB * NN * KNN)) - (char*)d_ws;
  if (ws_size < need) {
    fprintf(stderr, "kernel_launch: ws too small: %zu < %zu\n", ws_size, need);
    return;
  }

  // weight diffs
  sub_k<<<(HH * HH + 255) / 256, 256, 0, stream>>>(wqs, wks, WD, HH * HH);
  sub_k<<<(GS1 * GS1 + 255) / 256, 256, 0, stream>>>(wqs2, wks2, WD2, GS1 * GS1);

  // x = features^T @ fc1_w + fc1_b   (batched over B)
  gemm_k<true, 1><<<dim3(HH / 64, NN / 64, BB), 256, 0, stream>>>(
      features, fc1_w, fc1_b, X, nullptr, NN, HH, CC, NN, (ll)CC * NN, (ll)NN * HH);

  // branch 1: (B*N*4, 128) GEMM chain
  const int M1 = BB * NN * GNUM;
  gemm_k<false, 0><<<dim3(GS1 / 64, M1 / 64, 1), 256, 0, stream>>>(
      X, WD2, nullptr, P, nullptr, M1, GS1, GS1, GS1, 0, 0);
  gemm_k<false, 2><<<dim3(GS1 / 64, M1 / 64, 1), 256, 0, stream>>>(
      P, fgh1_w, fgh1_b, Q, nullptr, M1, GS1, GS1, GS1, 0, 0);
  gemm_k<false, 1><<<dim3(GS1 / 64, M1 / 64, 1), 256, 0, stream>>>(
      Q, fgh2_w, fgh2_b, P, nullptr, M1, GS1, GS1, GS1, 0, 0);
  softmax1_k<<<BB * GNUM, 1024, 0, stream>>>(P);

  // branch 2: gf2 = x[:, 3072:4096, :]
  gemm_k<false, 0><<<dim3(HH / 64, 1024 / 64, BB), 256, 0, stream>>>(
      X + (size_t)3072 * HH, WD, nullptr, S1, nullptr, 1024, HH, HH, HH, (ll)NN * HH, (ll)1024 * HH);
  gemm_k<false, 2><<<dim3(HH / 64, BB * 1024 / 64, 1), 256, 0, stream>>>(
      S1, fg1_w, fg1_b, S2, nullptr, BB * 1024, HH, HH, HH, 0, 0);
  gemm_k<false, 1><<<dim3(HH / 64, BB * 1024 / 64, 1), 256, 0, stream>>>(
      S2, fg2_w, fg2_b, S1, nullptr, BB * 1024, HH, HH, HH, 0, 0);
  softmax2_k<<<BB * 4, 1024, 0, stream>>>(S1);

  // v = x @ wvs
  gemm_k<false, 0><<<dim3(HH / 64, BB * NN / 64, 1), 256, 0, stream>>>(
      X, wvs, nullptr, V, nullptr, BB * NN, HH, HH, HH, 0, 0);

  // knn + pos-enc
  knn_k<<<BB * NN, 256, 0, stream>>>(xyz, IDX);
  posenc_k<<<BB * NN, 256, 0, stream>>>(xyz, IDX, fd1_w, fd1_b, Q);
  gemm_k<false, 3><<<dim3(HH / 64, BB * NN / 64, 1), 256, 0, stream>>>(
      Q, fd2_w, fd2_b, V, nullptr, BB * NN, HH, HH, HH, 0, 0);

  // res = (attn1 + attn2) * (v + posenc)  -> X
  res_k<<<(int)(BNH / 4 / 256), 256, 0, stream>>>(P, S1, V, X);

  // out = swap(res @ fc2_w + fc2_b) + features   (batched over B, transposed store)
  gemm_k<false, 4><<<dim3(CC / 64, NN / 64, BB), 256, 0, stream>>>(
      X, fc2_w, fc2_b, out, features, NN, CC, HH, HH, (ll)NN * HH, 0);

  // xyz passthrough
  copy_k<<<(BB * NN * 3 + 255) / 256, 256, 0, stream>>>(xyz, out + (size_t)BB * CC * NN, BB * NN * 3);
}

// Round 2
// 657.093 us; speedup vs baseline: 2.1116x; 2.1116x over previous
//
#include <hip/hip_runtime.h>
#include <cstdio>

typedef long long ll;
typedef __bf16 bf16x8 __attribute__((ext_vector_type(8)));
typedef float f32x4 __attribute__((ext_vector_type(4)));

#define BB 4
#define NN 4096
#define CC 256
#define HH 512
#define GNUM 4
#define GS1 128
#define KNN 10

#define SC1 0.08838834764831845f   // 1/sqrt(128)
#define SC2 0.044194173824159216f  // 1/sqrt(512)

__device__ inline unsigned pk2(float x, float y) {
  unsigned a = __float_as_uint(x), b = __float_as_uint(y);
  a = (a + 0x7FFFu + ((a >> 16) & 1u)) >> 16;
  b = (b + 0x7FFFu + ((b >> 16) & 1u)) >> 16;
  return a | (b << 16);
}
__device__ inline int sw16(int r) { return ((r ^ (r >> 3)) & 7) << 4; }

// ---------------- bf16 MFMA GEMM: C[m][n] = A[m][k] * B[k][n] ----------------
// ATRANS: A stored [k][m] with row stride lda.
// EPI: 0 store, 1 +bias, 2 +bias relu, 3 +bias accumulate, 4 +bias transposed store + pre
template<bool ATRANS, int EPI>
__global__ __launch_bounds__(256, 2) void mgemm_k(
    const float* __restrict__ A, const float* __restrict__ Bw,
    const float* __restrict__ bias, float* __restrict__ Cout,
    const float* __restrict__ pre,
    int M, int N, int K, int lda, ll strideA, ll strideC)
{
  const int z = blockIdx.z;
  A += (ll)z * strideA;
  const int bm = blockIdx.y * 128;
  const int bn = blockIdx.x * 128;
  __shared__ alignas(16) char smem[32768];
  char* smA = smem;
  char* smB = smem + 16384;
  const int tid = threadIdx.x;
  const int lane = tid & 63, w = tid >> 6;
  const int lr = lane & 15, lg = lane >> 4;
  const int wm = (w & 1) * 64, wn = (w >> 1) * 64;

  f32x4 acc[4][4] = {};

  for (int k0 = 0; k0 < K; k0 += 64) {
    // ---- stage A tile [128 m][64 k] as bf16, swizzled ----
    if (!ATRANS) {
      #pragma unroll
      for (int p = 0; p < 8; ++p) {
        const int r = p * 16 + (tid >> 4);
        const int c = (tid & 15) * 4;
        const float4 v = *reinterpret_cast<const float4*>(A + (ll)(bm + r) * lda + (k0 + c));
        *reinterpret_cast<uint2*>(smA + r * 128 + ((c * 2) ^ sw16(r))) =
            make_uint2(pk2(v.x, v.y), pk2(v.z, v.w));
      }
    } else {
      #pragma unroll
      for (int p = 0; p < 2; ++p) {
        const int bb = p * 256 + tid;
        const int mb = (bb & 31) * 4, kb = (bb >> 5) * 4;
        const float4 l0 = *reinterpret_cast<const float4*>(A + (ll)(k0 + kb + 0) * lda + (bm + mb));
        const float4 l1 = *reinterpret_cast<const float4*>(A + (ll)(k0 + kb + 1) * lda + (bm + mb));
        const float4 l2 = *reinterpret_cast<const float4*>(A + (ll)(k0 + kb + 2) * lda + (bm + mb));
        const float4 l3 = *reinterpret_cast<const float4*>(A + (ll)(k0 + kb + 3) * lda + (bm + mb));
        *reinterpret_cast<uint2*>(smA + (mb + 0) * 128 + ((kb * 2) ^ sw16(mb + 0))) = make_uint2(pk2(l0.x, l1.x), pk2(l2.x, l3.x));
        *reinterpret_cast<uint2*>(smA + (mb + 1) * 128 + ((kb * 2) ^ sw16(mb + 1))) = make_uint2(pk2(l0.y, l1.y), pk2(l2.y, l3.y));
        *reinterpret_cast<uint2*>(smA + (mb + 2) * 128 + ((kb * 2) ^ sw16(mb + 2))) = make_uint2(pk2(l0.z, l1.z), pk2(l2.z, l3.z));
        *reinterpret_cast<uint2*>(smA + (mb + 3) * 128 + ((kb * 2) ^ sw16(mb + 3))) = make_uint2(pk2(l0.w, l1.w), pk2(l2.w, l3.w));
      }
    }
    // ---- stage B tile transposed: Bst[128 n][64 k] ----
    #pragma unroll
    for (int p = 0; p < 2; ++p) {
      const int bb = p * 256 + tid;
      const int nb = (bb & 31) * 4, kb = (bb >> 5) * 4;
      const float4 l0 = *reinterpret_cast<const float4*>(Bw + (ll)(k0 + kb + 0) * N + (bn + nb));
      const float4 l1 = *reinterpret_cast<const float4*>(Bw + (ll)(k0 + kb + 1) * N + (bn + nb));
      const float4 l2 = *reinterpret_cast<const float4*>(Bw + (ll)(k0 + kb + 2) * N + (bn + nb));
      const float4 l3 = *reinterpret_cast<const float4*>(Bw + (ll)(k0 + kb + 3) * N + (bn + nb));
      *reinterpret_cast<uint2*>(smB + (nb + 0) * 128 + ((kb * 2) ^ sw16(nb + 0))) = make_uint2(pk2(l0.x, l1.x), pk2(l2.x, l3.x));
      *reinterpret_cast<uint2*>(smB + (nb + 1) * 128 + ((kb * 2) ^ sw16(nb + 1))) = make_uint2(pk2(l0.y, l1.y), pk2(l2.y, l3.y));
      *reinterpret_cast<uint2*>(smB + (nb + 2) * 128 + ((kb * 2) ^ sw16(nb + 2))) = make_uint2(pk2(l0.z, l1.z), pk2(l2.z, l3.z));
      *reinterpret_cast<uint2*>(smB + (nb + 3) * 128 + ((kb * 2) ^ sw16(nb + 3))) = make_uint2(pk2(l0.w, l1.w), pk2(l2.w, l3.w));
    }
    __syncthreads();

    // ---- MFMA: 2 k-steps of 32 ----
    #pragma unroll
    for (int ks = 0; ks < 2; ++ks) {
      bf16x8 af[4], bfr[4];
      #pragma unroll
      for (int mi = 0; mi < 4; ++mi) {
        const int r = wm + mi * 16 + lr;
        af[mi] = *reinterpret_cast<const bf16x8*>(smA + r * 128 + ((((ks << 2) + lg) << 4) ^ sw16(r)));
      }
      #pragma unroll
      for (int ni = 0; ni < 4; ++ni) {
        const int r = wn + ni * 16 + lr;
        bfr[ni] = *reinterpret_cast<const bf16x8*>(smB + r * 128 + ((((ks << 2) + lg) << 4) ^ sw16(r)));
      }
      #pragma unroll
      for (int mi = 0; mi < 4; ++mi)
        #pragma unroll
        for (int ni = 0; ni < 4; ++ni)
          acc[mi][ni] = __builtin_amdgcn_mfma_f32_16x16x32_bf16(af[mi], bfr[ni], acc[mi][ni], 0, 0, 0);
    }
    __syncthreads();
  }

  // ---- epilogue ----
  const ll cb = (ll)z * strideC;
  #pragma unroll
  for (int ni = 0; ni < 4; ++ni) {
    const int col = bn + wn + ni * 16 + lr;
    const float bv = (EPI != 0) ? bias[col] : 0.f;
    #pragma unroll
    for (int mi = 0; mi < 4; ++mi) {
      const int row0 = bm + wm + mi * 16 + lg * 4;
      if (EPI == 4) {
        const size_t o = ((size_t)z * N + col) * (size_t)M + row0;
        const float4 pv = *reinterpret_cast<const float4*>(pre + o);
        float4 r;
        r.x = acc[mi][ni][0] + bv + pv.x;
        r.y = acc[mi][ni][1] + bv + pv.y;
        r.z = acc[mi][ni][2] + bv + pv.z;
        r.w = acc[mi][ni][3] + bv + pv.w;
        *reinterpret_cast<float4*>(Cout + o) = r;
      } else {
        #pragma unroll
        for (int i = 0; i < 4; ++i) {
          float val = acc[mi][ni][i] + bv;
          if (EPI == 2) val = fmaxf(val, 0.f);
          if (EPI == 3) Cout[cb + (ll)(row0 + i) * N + col] += val;
          else          Cout[cb + (ll)(row0 + i) * N + col] = val;
        }
      }
    }
  }
}

// ---------------- online softmax partial reduce ----------------
__device__ inline void omax_upd(float& m, float& s, float v, float scale) {
  if (v > m) { s = s * expf((m - v) * scale) + 1.0f; m = v; }
  else       { s += expf((v - m) * scale); }
}
__device__ inline void omax_merge(float& m, float& s, float m2, float s2, float scale) {
  if (m2 > m) { s = s * expf((m - m2) * scale) + s2; m = m2; }
  else        { s += s2 * expf((m2 - m) * scale); }
}

// P (B,N,4,128), softmax over N. 512 blocks: (b, g, seg of 128 rows).
__global__ __launch_bounds__(256) void red1_k(const float* __restrict__ P,
                                              float* __restrict__ PM, float* __restrict__ PS) {
  const int bid = blockIdx.x;
  const int b = bid >> 7, g = (bid >> 5) & 3, seg = bid & 31;
  const int d = threadIdx.x & 127, half = threadIdx.x >> 7;
  const size_t base = (size_t)b * NN * HH + g * GS1 + d;
  float m = -3.4e38f, s = 0.f;
  const int n0 = seg * 128 + half * 64;
  for (int n = n0; n < n0 + 64; ++n)
    omax_upd(m, s, P[base + (size_t)n * HH], SC1);
  __shared__ float sm[256], ss[256];
  sm[threadIdx.x] = m; ss[threadIdx.x] = s;
  __syncthreads();
  if (half == 0) {
    omax_merge(m, s, sm[threadIdx.x + 128], ss[threadIdx.x + 128], SC1);
    const int c = b * HH + g * GS1 + d;
    PM[(size_t)seg * 2048 + c] = m;
    PS[(size_t)seg * 2048 + c] = s;
  }
}

// A2 (B,1024,512), softmax over rows. 128 blocks: (b, hblk, seg of 128 rows).
__global__ __launch_bounds__(256) void red2_k(const float* __restrict__ A2,
                                              float* __restrict__ PM, float* __restrict__ PS) {
  const int bid = blockIdx.x;
  const int b = bid >> 5, hb = (bid >> 3) & 3, seg = bid & 7;
  const int hl = threadIdx.x & 127, half = threadIdx.x >> 7;
  const int h = hb * 128 + hl;
  const size_t base = (size_t)b * 1024 * HH + h;
  float m = -3.4e38f, s = 0.f;
  const int r0 = seg * 128 + half * 64;
  for (int r = r0; r < r0 + 64; ++r)
    omax_upd(m, s, A2[base + (size_t)r * HH], SC2);
  __shared__ float sm[256], ss[256];
  sm[threadIdx.x] = m; ss[threadIdx.x] = s;
  __syncthreads();
  if (half == 0) {
    omax_merge(m, s, sm[threadIdx.x + 128], ss[threadIdx.x + 128], SC2);
    const int c = b * HH + h;
    PM[(size_t)seg * 2048 + c] = m;
    PS[(size_t)seg * 2048 + c] = s;
  }
}

__global__ __launch_bounds__(256) void combineN_k(const float* __restrict__ PM, const float* __restrict__ PS,
                                                  float* __restrict__ Mo, float* __restrict__ Ro,
                                                  int nseg, float scale) {
  const int c = blockIdx.x * 256 + threadIdx.x;
  float m = -3.4e38f, s = 0.f;
  for (int seg = 0; seg < nseg; ++seg)
    omax_merge(m, s, PM[(size_t)seg * 2048 + c], PS[(size_t)seg * 2048 + c], scale);
  Mo[c] = m;
  Ro[c] = 1.0f / s;
}

// ---------------- KNN top-10 ----------------
__global__ __launch_bounds__(256) void knn_k(const float* __restrict__ xyz, int* __restrict__ idx) {
  const int bn = blockIdx.x;
  const int b = bn >> 12, n = bn & (NN - 1);
  const float* xb = xyz + (size_t)b * NN * 3;
  const float qx = xb[n * 3], qy = xb[n * 3 + 1], qz = xb[n * 3 + 2];
  const float sq = fmaf(qz, qz, fmaf(qy, qy, qx * qx));

  float bd[KNN]; int bi[KNN];
  #pragma unroll
  for (int k = 0; k < KNN; ++k) { bd[k] = 3.4e38f; bi[k] = 1 << 30; }

  for (int m = threadIdx.x; m < NN; m += 256) {
    const float cx = xb[m * 3], cy = xb[m * 3 + 1], cz = xb[m * 3 + 2];
    const float sm = fmaf(cz, cz, fmaf(cy, cy, cx * cx));
    const float dot = fmaf(cz, qz, fmaf(cy, qy, cx * qx));
    const float dist = (sq + sm) - 2.0f * dot;
    if (dist < bd[KNN - 1]) {
      bd[KNN - 1] = dist; bi[KNN - 1] = m;
      #pragma unroll
      for (int k = KNN - 1; k >= 1; --k) {
        if (bd[k] < bd[k - 1]) {
          float td = bd[k]; bd[k] = bd[k - 1]; bd[k - 1] = td;
          int ti = bi[k]; bi[k] = bi[k - 1]; bi[k - 1] = ti;
        }
      }
    }
  }

  __shared__ float md[256][KNN];
  __shared__ int mi[256][KNN];
  const int tid = threadIdx.x;
  #pragma unroll
  for (int k = 0; k < KNN; ++k) { md[tid][k] = bd[k]; mi[tid][k] = bi[k]; }
  __syncthreads();

  for (int s = 1; s < 256; s <<= 1) {
    if ((tid & (2 * s - 1)) == 0) {
      float od[KNN]; int oi[KNN];
      int pa = 0, pb = 0;
      #pragma unroll
      for (int k = 0; k < KNN; ++k) {
        const float da = md[tid][pa], db = md[tid + s][pb];
        const int ia = mi[tid][pa], ib = mi[tid + s][pb];
        const bool takea = (da < db) || (da == db && ia < ib);
        od[k] = takea ? da : db;
        oi[k] = takea ? ia : ib;
        if (takea) ++pa; else ++pb;
      }
      #pragma unroll
      for (int k = 0; k < KNN; ++k) { md[tid][k] = od[k]; mi[tid][k] = oi[k]; }
    }
    __syncthreads();
  }
  if (tid < KNN) idx[(size_t)bn * KNN + tid] = mi[0][tid];
}

// ---------------- pos-enc hidden mean ----------------
__global__ __launch_bounds__(256) void posenc_k(const float* __restrict__ xyz, const int* __restrict__ idx,
                                                const float* __restrict__ fd1w, const float* __restrict__ fd1b,
                                                float* __restrict__ hmean) {
  const int bn = blockIdx.x;
  const int b = bn >> 12, n = bn & (NN - 1);
  const float* xb = xyz + (size_t)b * NN * 3;
  const float qx = xb[n * 3], qy = xb[n * 3 + 1], qz = xb[n * 3 + 2];
  __shared__ float dxyz[KNN][3];
  if (threadIdx.x < KNN) {
    const int m = idx[(size_t)bn * KNN + threadIdx.x];
    dxyz[threadIdx.x][0] = qx - xb[m * 3];
    dxyz[threadIdx.x][1] = qy - xb[m * 3 + 1];
    dxyz[threadIdx.x][2] = qz - xb[m * 3 + 2];
  }
  __syncthreads();
  for (int h = threadIdx.x; h < HH; h += 256) {
    const float w0 = fd1w[h], w1 = fd1w[HH + h], w2 = fd1w[2 * HH + h], bb = fd1b[h];
    float acc = 0.f;
    #pragma unroll
    for (int k = 0; k < KNN; ++k)
      acc += fmaxf(fmaf(dxyz[k][2], w2, fmaf(dxyz[k][1], w1, dxyz[k][0] * w0)) + bb, 0.f);
    hmean[(size_t)bn * HH + h] = acc * 0.1f;
  }
}

// ---------------- res = (softmax1(P) + softmax2(A2)) * (v + posenc), normalize fused ----------------
__global__ __launch_bounds__(256) void res_k(const float* __restrict__ P, const float* __restrict__ A2,
                                             const float* __restrict__ V,
                                             const float* __restrict__ M1, const float* __restrict__ R1,
                                             const float* __restrict__ M2, const float* __restrict__ R2,
                                             float* __restrict__ R) {
  const size_t i4 = (size_t)blockIdx.x * 256 + threadIdx.x;
  const size_t i = i4 * 4;
  const int b = (int)(i >> 21);
  const int n = (int)((i >> 9) & (NN - 1));
  const int h = (int)(i & (HH - 1));
  const int c = (b << 9) + h;
  const size_t j = (((size_t)b * 1024 + (n & 1023)) << 9) + h;
  const float4 p = *reinterpret_cast<const float4*>(P + i);
  const float4 a = *reinterpret_cast<const float4*>(A2 + j);
  const float4 v = *reinterpret_cast<const float4*>(V + i);
  const float4 m1 = *reinterpret_cast<const float4*>(M1 + c);
  const float4 r1 = *reinterpret_cast<const float4*>(R1 + c);
  const float4 m2 = *reinterpret_cast<const float4*>(M2 + c);
  const float4 r2 = *reinterpret_cast<const float4*>(R2 + c);
  float4 r;
  r.x = (expf((p.x - m1.x) * SC1) * r1.x + expf((a.x - m2.x) * SC2) * r2.x) * v.x;
  r.y = (expf((p.y - m1.y) * SC1) * r1.y + expf((a.y - m2.y) * SC2) * r2.y) * v.y;
  r.z = (expf((p.z - m1.z) * SC1) * r1.z + expf((a.z - m2.z) * SC2) * r2.z) * v.z;
  r.w = (expf((p.w - m1.w) * SC1) * r1.w + expf((a.w - m2.w) * SC2) * r2.w) * v.w;
  *reinterpret_cast<float4*>(R + i) = r;
}

__global__ void sub_k(const float* __restrict__ a, const float* __restrict__ b, float* __restrict__ o, int n) {
  const int i = blockIdx.x * 256 + threadIdx.x;
  if (i < n) o[i] = a[i] - b[i];
}

__global__ void copy_k(const float* __restrict__ a, float* __restrict__ o, int n) {
  const int i = blockIdx.x * 256 + threadIdx.x;
  if (i < n) o[i] = a[i];
}

extern "C" void kernel_launch(void* const* d_in, const int* in_sizes, int n_in,
                              void* d_out, int out_size, void* d_ws, size_t ws_size,
                              hipStream_t stream) {
  const float* features = (const float*)d_in[0];
  const float* xyz      = (const float*)d_in[1];
  const float* fc1_w    = (const float*)d_in[2];
  const float* fc1_b    = (const float*)d_in[3];
  const float* fc2_w    = (const float*)d_in[4];
  const float* fc2_b    = (const float*)d_in[5];
  const float* fd1_w    = (const float*)d_in[6];
  const float* fd1_b    = (const float*)d_in[7];
  const float* fd2_w    = (const float*)d_in[8];
  const float* fd2_b    = (const float*)d_in[9];
  const float* fg1_w    = (const float*)d_in[10];
  const float* fg1_b    = (const float*)d_in[11];
  const float* fg2_w    = (const float*)d_in[12];
  const float* fg2_b    = (const float*)d_in[13];
  const float* fgh1_w   = (const float*)d_in[14];
  const float* fgh1_b   = (const float*)d_in[15];
  const float* fgh2_w   = (const float*)d_in[16];
  const float* fgh2_b   = (const float*)d_in[17];
  const float* wqs      = (const float*)d_in[18];
  const float* wks      = (const float*)d_in[19];
  const float* wvs      = (const float*)d_in[20];
  const float* wqs2     = (const float*)d_in[21];
  const float* wks2     = (const float*)d_in[22];
  float* out = (float*)d_out;

  const size_t BNH = (size_t)BB * NN * HH;        // 8388608
  float* X   = (float*)d_ws;                      // x, later res
  float* P   = X + BNH;                           // raw branch-1 scores
  float* Q   = P + BNH;                           // U1, later posenc hmean
  float* V   = Q + BNH;                           // v, then += posenc
  float* S1  = V + BNH;                           // raw branch-2 scores
  float* S2  = S1 + (size_t)BB * 1024 * HH;       // U2
  float* WD  = S2 + (size_t)BB * 1024 * HH;       // wqs-wks
  float* WD2 = WD + HH * HH;                      // wqs2-wks2
  int*   IDX = (int*)(WD2 + GS1 * GS1);           // knn indices
  float* PM1 = (float*)(IDX + (size_t)BB * NN * KNN);
  float* PS1 = PM1 + 32 * 2048;
  float* PM2 = PS1 + 32 * 2048;
  float* PS2 = PM2 + 8 * 2048;
  float* M1  = PS2 + 8 * 2048;
  float* R1  = M1 + 2048;
  float* M2  = R1 + 2048;
  float* R2  = M2 + 2048;
  const size_t need = ((char*)(R2 + 2048)) - (char*)d_ws;
  if (ws_size < need) {
    fprintf(stderr, "kernel_launch: ws too small: %zu < %zu\n", ws_size, need);
    return;
  }

  // weight diffs
  sub_k<<<(HH * HH + 255) / 256, 256, 0, stream>>>(wqs, wks, WD, HH * HH);
  sub_k<<<(GS1 * GS1 + 255) / 256, 256, 0, stream>>>(wqs2, wks2, WD2, GS1 * GS1);

  // x = features^T @ fc1_w + fc1_b
  mgemm_k<true, 1><<<dim3(HH / 128, NN / 128, BB), 256, 0, stream>>>(
      features, fc1_w, fc1_b, X, nullptr, NN, HH, CC, NN, (ll)CC * NN, (ll)NN * HH);

  // branch 1: (B*N*4, 128) GEMM chain
  const int M1r = BB * NN * GNUM;
  mgemm_k<false, 0><<<dim3(1, M1r / 128, 1), 256, 0, stream>>>(
      X, WD2, nullptr, P, nullptr, M1r, GS1, GS1, GS1, 0, 0);
  mgemm_k<false, 2><<<dim3(1, M1r / 128, 1), 256, 0, stream>>>(
      P, fgh1_w, fgh1_b, Q, nullptr, M1r, GS1, GS1, GS1, 0, 0);
  mgemm_k<false, 1><<<dim3(1, M1r / 128, 1), 256, 0, stream>>>(
      Q, fgh2_w, fgh2_b, P, nullptr, M1r, GS1, GS1, GS1, 0, 0);
  red1_k<<<512, 256, 0, stream>>>(P, PM1, PS1);
  combineN_k<<<8, 256, 0, stream>>>(PM1, PS1, M1, R1, 32, SC1);

  // branch 2
  mgemm_k<false, 0><<<dim3(HH / 128, 1024 / 128, BB), 256, 0, stream>>>(
      X + (size_t)3072 * HH, WD, nullptr, S1, nullptr, 1024, HH, HH, HH, (ll)NN * HH, (ll)1024 * HH);
  mgemm_k<false, 2><<<dim3(HH / 128, BB * 1024 / 128, 1), 256, 0, stream>>>(
      S1, fg1_w, fg1_b, S2, nullptr, BB * 1024, HH, HH, HH, 0, 0);
  mgemm_k<false, 1><<<dim3(HH / 128, BB * 1024 / 128, 1), 256, 0, stream>>>(
      S2, fg2_w, fg2_b, S1, nullptr, BB * 1024, HH, HH, HH, 0, 0);
  red2_k<<<128, 256, 0, stream>>>(S1, PM2, PS2);
  combineN_k<<<8, 256, 0, stream>>>(PM2, PS2, M2, R2, 8, SC2);

  // v = x @ wvs
  mgemm_k<false, 0><<<dim3(HH / 128, BB * NN / 128, 1), 256, 0, stream>>>(
      X, wvs, nullptr, V, nullptr, BB * NN, HH, HH, HH, 0, 0);

  // knn + pos-enc
  knn_k<<<BB * NN, 256, 0, stream>>>(xyz, IDX);
  posenc_k<<<BB * NN, 256, 0, stream>>>(xyz, IDX, fd1_w, fd1_b, Q);
  mgemm_k<false, 3><<<dim3(HH / 128, BB * NN / 128, 1), 256, 0, stream>>>(
      Q, fd2_w, fd2_b, V, nullptr, BB * NN, HH, HH, HH, 0, 0);

  // res = (attn1 + attn2) * (v + posenc)  -> X
  res_k<<<(int)(BNH / 4 / 256), 256, 0, stream>>>(P, S1, V, M1, R1, M2, R2, X);

  // out = swap(res @ fc2_w + fc2_b) + features
  mgemm_k<false, 4><<<dim3(CC / 128, NN / 128, BB), 256, 0, stream>>>(
      X, fc2_w, fc2_b, out, features, NN, CC, HH, HH, (ll)NN * HH, 0);

  // xyz passthrough
  copy_k<<<(BB * NN * 3 + 255) / 256, 256, 0, stream>>>(xyz, out + (size_t)BB * CC * NN, BB * NN * 3);
}